// Round 8
// baseline (195.183 us; speedup 1.0000x reference)
//
#include <hip/hip_runtime.h>
#include <math.h>

using short8 = __attribute__((ext_vector_type(8))) short;   // 8 bf16 in 4 VGPRs
using f32x4  = __attribute__((ext_vector_type(4))) float;
using us4    = __attribute__((ext_vector_type(4))) unsigned short;
typedef unsigned short ushort_t;

#define MFMA16(a,b,c) __builtin_amdgcn_mfma_f32_16x16x32_bf16((a),(b),(c),0,0,0)

#define BB 2
#define TT 2048
#define CC 512
#define HH 8
#define DD 64
#define N3 1536
#define NCH 32   // chunks of 64 along T

__device__ __forceinline__ float bf2f(ushort_t u){ unsigned int x=((unsigned int)u)<<16; return __builtin_bit_cast(float,x); }
__device__ __forceinline__ ushort_t f2bf(float f){ unsigned int u=__builtin_bit_cast(unsigned int,f); u += 0x7FFFu + ((u>>16)&1u); return (ushort_t)(u>>16); }
__device__ __forceinline__ float elu1(float v){ return v > 0.f ? v + 1.f : expf(v); }

// ---------- prep: coalesced tiled transposes + vectorized casts ----------
__global__ __launch_bounds__(256) void prep(const float* __restrict__ x, const float* __restrict__ amask,
                     const float* __restrict__ W, const float* __restrict__ Pw,
                     ushort_t* __restrict__ xb, ushort_t* __restrict__ wt,
                     ushort_t* __restrict__ pt, float* __restrict__ mdiag)
{
  __shared__ float tile[32][33];
  int bid = blockIdx.x, tid = threadIdx.x;
  int tx = tid & 31, ty0 = tid >> 5;
  if (bid < 768) {                       // W (512x1536) -> wt (1536x512)
    int nt = bid % 48, kt = bid / 48;
    #pragma unroll
    for (int i=0;i<4;++i){ int ty=ty0+8*i; tile[ty][tx] = W[(size_t)(kt*32+ty)*N3 + nt*32+tx]; }
    __syncthreads();
    #pragma unroll
    for (int i=0;i<4;++i){ int ty=ty0+8*i; wt[(size_t)(nt*32+ty)*CC + kt*32+tx] = f2bf(tile[tx][ty]); }
  } else if (bid < 1024) {               // Pw (512x512) -> pt (512x512 transposed)
    int tt = bid - 768; int nt = tt & 15, kt = tt >> 4;
    #pragma unroll
    for (int i=0;i<4;++i){ int ty=ty0+8*i; tile[ty][tx] = Pw[(size_t)(kt*32+ty)*CC + nt*32+tx]; }
    __syncthreads();
    #pragma unroll
    for (int i=0;i<4;++i){ int ty=ty0+8*i; pt[(size_t)(nt*32+ty)*CC + kt*32+tx] = f2bf(tile[tx][ty]); }
  } else if (bid < 1056) {               // x cast f32 -> bf16, float4-wide
    int g = (bid-1024)*256 + tid;
    const f32x4* xs = (const f32x4*)x;
    us4* xo = (us4*)xb;
    for (int i=g; i<(BB*TT*CC)/4; i+=32*256) {
      f32x4 v = xs[i];
      us4 o = { f2bf(v[0]), f2bf(v[1]), f2bf(v[2]), f2bf(v[3]) };
      xo[i] = o;
    }
  } else {                               // mask diagonal
    for (int i=tid; i<BB*TT; i+=256) { int b=i>>11, t=i&2047; mdiag[i]=amask[((size_t)b*TT+t)*TT+t]; }
  }
}

// ---------- GEMM1: qkv = x @ Wqkv + b, fused elu+1/mask, emits Q,K row-major + K^T,V^T ----------
__global__ __launch_bounds__(256) void gemm_qkv(const ushort_t* __restrict__ A, const ushort_t* __restrict__ Bt,
    const float* __restrict__ bias, const float* __restrict__ mdiag,
    ushort_t* __restrict__ phiQ, ushort_t* __restrict__ phiK,
    ushort_t* __restrict__ kT, ushort_t* __restrict__ vT)
{
  __shared__ __align__(16) ushort_t lA[128][40];
  __shared__ __align__(16) ushort_t lB[128][40];
  const int tid = threadIdx.x;
  const int lane = tid & 63, wid = tid >> 6;
  const int g = lane >> 4, lr = lane & 15;
  const int bm = blockIdx.y * 128, bn = blockIdx.x * 128;
  const int wm = (wid >> 1) * 64, wn = (wid & 1) * 64;
  f32x4 acc[4][4] = {};
  for (int k0 = 0; k0 < CC; k0 += 32) {
    #pragma unroll
    for (int it = 0; it < 2; ++it) {
      int flat = tid + it * 256;
      int row = flat >> 2, seg = flat & 3;
      *(short8*)&lA[row][seg*8] = *(const short8*)&A[(size_t)(bm+row)*CC + k0 + seg*8];
      *(short8*)&lB[row][seg*8] = *(const short8*)&Bt[(size_t)(bn+row)*CC + k0 + seg*8];
    }
    __syncthreads();
    short8 af[4], bf[4];
    #pragma unroll
    for (int mf=0;mf<4;++mf) af[mf] = *(const short8*)&lA[wm+mf*16+lr][g*8];
    #pragma unroll
    for (int nf=0;nf<4;++nf) bf[nf] = *(const short8*)&lB[wn+nf*16+lr][g*8];
    #pragma unroll
    for (int mf=0;mf<4;++mf)
      #pragma unroll
      for (int nf=0;nf<4;++nf)
        acc[mf][nf] = MFMA16(af[mf], bf[nf], acc[mf][nf]);
    __syncthreads();
  }
  #pragma unroll
  for (int mf=0;mf<4;++mf) {
    int m0 = bm + wm + mf*16 + g*4;
    #pragma unroll
    for (int nf=0;nf<4;++nf) {
      int n = bn + wn + nf*16 + lr;
      int which = n >> 9, h = (n >> 6) & 7, d = n & 63;
      #pragma unroll
      for (int r=0;r<4;++r) {
        int mm = m0 + r;
        int b = mm >> 11, t = mm & 2047;
        float v = acc[mf][nf][r] + bias[n];
        size_t bh = (size_t)(b*HH + h);
        size_t oidx = (bh*TT + t)*DD + d;
        if (which == 0)       phiQ[oidx] = f2bf(elu1(v));
        else if (which == 1)  { ushort_t e = f2bf(elu1(v) * mdiag[mm]); phiK[oidx] = e; kT[(bh*DD + d)*TT + t] = e; }
        else                  vT[(bh*DD + d)*TT + t] = f2bf(v * mdiag[mm]);
      }
    }
  }
}

// ---------- per-chunk state from K^T/V^T global fragments (no LDS) ----------
// sChunk[cid][j][i] = sum_t V_aug[t][j] * phiK[t][i]   (j=64 row: ones)
__global__ __launch_bounds__(256) void chunk_state(const ushort_t* __restrict__ kT,
                                                   const ushort_t* __restrict__ vT,
                                                   float* __restrict__ sChunk)
{
  int wid = threadIdx.x >> 6;
  int cid = blockIdx.x * 4 + wid;        // 0..511
  int bh = cid >> 5, c = cid & 31;
  int lane = threadIdx.x & 63, g = lane >> 4, lr = lane & 15;
  int t0 = c * 64;
  short8 af[4][2];
  #pragma unroll
  for (int mf=0;mf<4;++mf)
    #pragma unroll
    for (int kf=0;kf<2;++kf)
      af[mf][kf] = *(const short8*)&kT[((size_t)bh*DD + mf*16+lr)*TT + t0 + kf*32 + g*8];
  short8 onesf;
  {
    short ov = (lr == 0) ? (short)0x3F80 : (short)0;
    #pragma unroll
    for (int j=0;j<8;++j) onesf[j] = ov;
  }
  float* dst = &sChunk[(size_t)cid * 5120];
  #pragma unroll
  for (int nf=0;nf<5;++nf) {
    short8 bfr[2];
    #pragma unroll
    for (int kf=0;kf<2;++kf)
      bfr[kf] = (nf < 4) ? *(const short8*)&vT[((size_t)bh*DD + nf*16+lr)*TT + t0 + kf*32 + g*8]
                         : onesf;
    #pragma unroll
    for (int mf=0;mf<4;++mf) {
      f32x4 acc = {0.f,0.f,0.f,0.f};
      #pragma unroll
      for (int kf=0;kf<2;++kf) acc = MFMA16(af[mf][kf], bfr[kf], acc);
      *(f32x4*)&dst[(size_t)(nf*16+lr)*64 + mf*16 + g*4] = acc;
    }
  }
}

// ---------- exclusive prefix over chunks: float4 + prefetch ----------
__global__ __launch_bounds__(256) void scan_states(const float* __restrict__ sChunk, ushort_t* __restrict__ sPrev)
{
  int bx = blockIdx.x;                   // 80 blocks: 16 bh x 5 segs
  int bh = bx / 5, seg = bx % 5;
  int e4 = seg*256 + threadIdx.x;        // 0..1279 float4 columns
  const f32x4* src = (const f32x4*)(sChunk + (size_t)bh*NCH*5120) + e4;
  us4* dst = (us4*)(sPrev + (size_t)bh*NCH*5120) + e4;
  f32x4 run = {0.f,0.f,0.f,0.f};
  f32x4 nxt = src[0];
  for (int c = 0; c < NCH; ++c) {
    f32x4 cur = nxt;
    if (c+1 < NCH) nxt = src[(size_t)(c+1)*1280];
    us4 o = { f2bf(run[0]), f2bf(run[1]), f2bf(run[2]), f2bf(run[3]) };
    dst[(size_t)c*1280] = o;
    run += cur;
  }
}

// ---------- per-chunk output: y = (Q@S_prev + tril(QK^T)@V) / den ----------
__global__ __launch_bounds__(256) void chunk_out(const ushort_t* __restrict__ phiQ,
    const ushort_t* __restrict__ phiK, const ushort_t* __restrict__ vT,
    const ushort_t* __restrict__ sPrev, ushort_t* __restrict__ ya)
{
  __shared__ __align__(16) ushort_t P[4][64][72];
  int wid = threadIdx.x >> 6;
  int cid = blockIdx.x * 4 + wid;
  int bh = cid >> 5, c = cid & 31;
  int lane = threadIdx.x & 63, g = lane >> 4, lr = lane & 15;
  int t0 = c * 64;
  size_t qbase = (size_t)bh*TT + t0;
  // Q fragments (reused for QK^T and Q@S)
  short8 qf[4][2];
  #pragma unroll
  for (int mf=0;mf<4;++mf)
    #pragma unroll
    for (int kf=0;kf<2;++kf)
      qf[mf][kf] = *(const short8*)&phiQ[(qbase + mf*16 + lr)*DD + kf*32 + g*8];
  // QK^T
  f32x4 accs[4][4] = {};
  #pragma unroll
  for (int nf=0;nf<4;++nf)
    #pragma unroll
    for (int kf=0;kf<2;++kf) {
      short8 bk = *(const short8*)&phiK[(qbase + nf*16 + lr)*DD + kf*32 + g*8];
      #pragma unroll
      for (int mf=0;mf<4;++mf) accs[mf][nf] = MFMA16(qf[mf][kf], bk, accs[mf][nf]);
    }
  // Q @ S_prev (cols 0..63 numerator, col 64 = denominator prefix)
  f32x4 accn[4][5] = {};
  size_t sbase = (size_t)cid * 5120;
  #pragma unroll
  for (int nf=0;nf<5;++nf)
    #pragma unroll
    for (int kf=0;kf<2;++kf) {
      short8 bs = *(const short8*)&sPrev[sbase + (size_t)(nf*16+lr)*64 + kf*32 + g*8];
      #pragma unroll
      for (int mf=0;mf<4;++mf) accn[mf][nf] = MFMA16(qf[mf][kf], bs, accn[mf][nf]);
    }
  // masked P -> LDS (bf16)
  #pragma unroll
  for (int mf=0;mf<4;++mf)
    #pragma unroll
    for (int nf=0;nf<4;++nf)
      #pragma unroll
      for (int r=0;r<4;++r) {
        int t = mf*16 + g*4 + r, s = nf*16 + lr;
        P[wid][t][s] = f2bf((s <= t) ? accs[mf][nf][r] : 0.f);
      }
  __syncthreads();
  short8 pf[4][2];
  #pragma unroll
  for (int mf=0;mf<4;++mf)
    #pragma unroll
    for (int kf=0;kf<2;++kf)
      pf[mf][kf] = *(const short8*)&P[wid][mf*16+lr][kf*32 + g*8];
  // P @ V_aug (V^T from global; ones row synthesized -> rowsum(P) joins accn[:,64])
  short8 onesf;
  {
    short ov = (lr == 0) ? (short)0x3F80 : (short)0;
    #pragma unroll
    for (int j=0;j<8;++j) onesf[j] = ov;
  }
  #pragma unroll
  for (int nf=0;nf<5;++nf)
    #pragma unroll
    for (int kf=0;kf<2;++kf) {
      short8 vf = (nf < 4) ? *(const short8*)&vT[((size_t)bh*DD + nf*16+lr)*TT + t0 + kf*32 + g*8]
                           : onesf;
      #pragma unroll
      for (int mf=0;mf<4;++mf) accn[mf][nf] = MFMA16(pf[mf][kf], vf, accn[mf][nf]);
    }
  // denominator: accn[mf][4][r] lives in lanes lr==0; broadcast across 16-lane group
  float invb[4][4];
  #pragma unroll
  for (int mf=0;mf<4;++mf)
    #pragma unroll
    for (int r=0;r<4;++r) {
      float iv = 1.0f / fmaxf(accn[mf][4][r], 1e-8f);
      invb[mf][r] = __shfl(iv, lane & 48);
    }
  int b = bh >> 3, h = bh & 7;
  #pragma unroll
  for (int mf=0;mf<4;++mf)
    #pragma unroll
    for (int nf=0;nf<4;++nf)
      #pragma unroll
      for (int r=0;r<4;++r) {
        int t = t0 + mf*16 + g*4 + r;
        int col = h*64 + nf*16 + lr;
        ya[((size_t)b*TT + t)*CC + col] = f2bf(accn[mf][nf][r] * invb[mf][r]);
      }
}

// ---------- GEMM3: out = ya @ c_proj + bias (fp32 out) ----------
__global__ __launch_bounds__(256) void gemm_proj(const ushort_t* __restrict__ A, const ushort_t* __restrict__ Bt,
                                                 const float* __restrict__ bias, float* __restrict__ out)
{
  __shared__ __align__(16) ushort_t lA[128][40];
  __shared__ __align__(16) ushort_t lB[128][40];
  const int tid = threadIdx.x;
  const int lane = tid & 63, wid = tid >> 6;
  const int g = lane >> 4, lr = lane & 15;
  const int bm = blockIdx.y * 128, bn = blockIdx.x * 128;
  const int wm = (wid >> 1) * 64, wn = (wid & 1) * 64;
  f32x4 acc[4][4] = {};
  for (int k0 = 0; k0 < CC; k0 += 32) {
    #pragma unroll
    for (int it = 0; it < 2; ++it) {
      int flat = tid + it * 256;
      int row = flat >> 2, seg = flat & 3;
      *(short8*)&lA[row][seg*8] = *(const short8*)&A[(size_t)(bm+row)*CC + k0 + seg*8];
      *(short8*)&lB[row][seg*8] = *(const short8*)&Bt[(size_t)(bn+row)*CC + k0 + seg*8];
    }
    __syncthreads();
    short8 af[4], bf[4];
    #pragma unroll
    for (int mf=0;mf<4;++mf) af[mf] = *(const short8*)&lA[wm+mf*16+lr][g*8];
    #pragma unroll
    for (int nf=0;nf<4;++nf) bf[nf] = *(const short8*)&lB[wn+nf*16+lr][g*8];
    #pragma unroll
    for (int mf=0;mf<4;++mf)
      #pragma unroll
      for (int nf=0;nf<4;++nf)
        acc[mf][nf] = MFMA16(af[mf], bf[nf], acc[mf][nf]);
    __syncthreads();
  }
  #pragma unroll
  for (int mf=0;mf<4;++mf) {
    int m0 = bm + wm + mf*16 + g*4;
    #pragma unroll
    for (int nf=0;nf<4;++nf) {
      int n = bn + wn + nf*16 + lr;
      #pragma unroll
      for (int r=0;r<4;++r)
        out[(size_t)(m0 + r)*CC + n] = acc[mf][nf][r] + bias[n];
    }
  }
}

extern "C" void kernel_launch(void* const* d_in, const int* in_sizes, int n_in,
                              void* d_out, int out_size, void* d_ws, size_t ws_size,
                              hipStream_t stream)
{
  const float* x     = (const float*)d_in[0];
  const float* amask = (const float*)d_in[1];
  const float* wqkv  = (const float*)d_in[2];
  const float* bqkv  = (const float*)d_in[3];
  const float* wproj = (const float*)d_in[4];
  const float* bproj = (const float*)d_in[5];
  float* out = (float*)d_out;
  char* ws = (char*)d_ws;

  ushort_t* xb    = (ushort_t*)(ws + 0);          // 4096x512 bf16      (4 MB)
  ushort_t* wt    = (ushort_t*)(ws + 4194304);    // 1536x512 bf16      (1.5 MB)
  ushort_t* pt    = (ushort_t*)(ws + 5767168);    // 512x512 bf16       (0.5 MB)
  float*    mdiag = (float*)   (ws + 6291456);    // 4096 f32
  ushort_t* phiQ  = (ushort_t*)(ws + 6307840);    // [bh][t][d] bf16    (4 MB)
  ushort_t* phiK  = (ushort_t*)(ws + 10502144);   // [bh][t][d] bf16    (4 MB)
  ushort_t* kT    = (ushort_t*)(ws + 14696448);   // [bh][d][t] bf16    (4 MB)
  ushort_t* vT    = (ushort_t*)(ws + 18890752);   // [bh][d][t] bf16    (4 MB)
  ushort_t* ya    = (ushort_t*)(ws + 23085056);   // 4096x512 bf16      (4 MB)
  float*    sChunk= (float*)   (ws + 27279360);   // 512 x 80x64 f32    (10.5 MB)
  ushort_t* sPrev = (ushort_t*)(ws + 37765120);   // 512 x 80x64 bf16   (5.25 MB)

  prep<<<dim3(1057), dim3(256), 0, stream>>>(x, amask, wqkv, wproj, xb, wt, pt, mdiag);
  gemm_qkv<<<dim3(12,32), dim3(256), 0, stream>>>(xb, wt, bqkv, mdiag, phiQ, phiK, kT, vT);
  chunk_state<<<dim3(128), dim3(256), 0, stream>>>(kT, vT, sChunk);
  scan_states<<<dim3(80), dim3(256), 0, stream>>>(sChunk, sPrev);
  chunk_out<<<dim3(128), dim3(256), 0, stream>>>(phiQ, phiK, vT, sPrev, ya);
  gemm_proj<<<dim3(4,32), dim3(256), 0, stream>>>(ya, pt, bproj, out);
}

// Round 9
// 167.660 us; speedup vs baseline: 1.1642x; 1.1642x over previous
//
#include <hip/hip_runtime.h>
#include <math.h>

using short8 = __attribute__((ext_vector_type(8))) short;   // 8 bf16 in 4 VGPRs
using f32x4  = __attribute__((ext_vector_type(4))) float;
using us4    = __attribute__((ext_vector_type(4))) unsigned short;
typedef unsigned short ushort_t;

#define MFMA16(a,b,c) __builtin_amdgcn_mfma_f32_16x16x32_bf16((a),(b),(c),0,0,0)

#define BB 2
#define TT 2048
#define CC 512
#define HH 8
#define DD 64
#define N3 1536
#define NCH 32   // chunks of 64 along T

__device__ __forceinline__ float bf2f(ushort_t u){ unsigned int x=((unsigned int)u)<<16; return __builtin_bit_cast(float,x); }
__device__ __forceinline__ ushort_t f2bf(float f){ unsigned int u=__builtin_bit_cast(unsigned int,f); u += 0x7FFFu + ((u>>16)&1u); return (ushort_t)(u>>16); }
__device__ __forceinline__ float elu1(float v){ return v > 0.f ? v + 1.f : expf(v); }

// ---------- prep: coalesced tiled transposes + vectorized casts (unchanged) ----------
__global__ __launch_bounds__(256) void prep(const float* __restrict__ x, const float* __restrict__ amask,
                     const float* __restrict__ W, const float* __restrict__ Pw,
                     ushort_t* __restrict__ xb, ushort_t* __restrict__ wt,
                     ushort_t* __restrict__ pt, float* __restrict__ mdiag)
{
  __shared__ float tile[32][33];
  int bid = blockIdx.x, tid = threadIdx.x;
  int tx = tid & 31, ty0 = tid >> 5;
  if (bid < 768) {                       // W (512x1536) -> wt (1536x512)
    int nt = bid % 48, kt = bid / 48;
    #pragma unroll
    for (int i=0;i<4;++i){ int ty=ty0+8*i; tile[ty][tx] = W[(size_t)(kt*32+ty)*N3 + nt*32+tx]; }
    __syncthreads();
    #pragma unroll
    for (int i=0;i<4;++i){ int ty=ty0+8*i; wt[(size_t)(nt*32+ty)*CC + kt*32+tx] = f2bf(tile[tx][ty]); }
  } else if (bid < 1024) {               // Pw (512x512) -> pt transposed
    int tt = bid - 768; int nt = tt & 15, kt = tt >> 4;
    #pragma unroll
    for (int i=0;i<4;++i){ int ty=ty0+8*i; tile[ty][tx] = Pw[(size_t)(kt*32+ty)*CC + nt*32+tx]; }
    __syncthreads();
    #pragma unroll
    for (int i=0;i<4;++i){ int ty=ty0+8*i; pt[(size_t)(nt*32+ty)*CC + kt*32+tx] = f2bf(tile[tx][ty]); }
  } else if (bid < 1056) {               // x cast f32 -> bf16, float4-wide
    int g = (bid-1024)*256 + tid;
    const f32x4* xs = (const f32x4*)x;
    us4* xo = (us4*)xb;
    for (int i=g; i<(BB*TT*CC)/4; i+=32*256) {
      f32x4 v = xs[i];
      us4 o = { f2bf(v[0]), f2bf(v[1]), f2bf(v[2]), f2bf(v[3]) };
      xo[i] = o;
    }
  } else {                               // mask diagonal
    for (int i=tid; i<BB*TT; i+=256) { int b=i>>11, t=i&2047; mdiag[i]=amask[((size_t)b*TT+t)*TT+t]; }
  }
}

// ---------- GEMM1: 128x64 tile, BK=64, reg-staged pipeline; epilogue: phiQ/phiK direct, kTc/vTc via LDS transpose ----------
// grid (24, 32): x = n-block (64 cols, one head of one third), y = m-block (128 rows = 2 chunks)
__global__ __launch_bounds__(256) void gemm_qkv(const ushort_t* __restrict__ A, const ushort_t* __restrict__ Bt,
    const float* __restrict__ bias, const float* __restrict__ mdiag,
    ushort_t* __restrict__ phiQ, ushort_t* __restrict__ phiK,
    ushort_t* __restrict__ kTc, ushort_t* __restrict__ vTc)
{
  __shared__ __align__(16) ushort_t smem[128*72 + 64*72];
  ushort_t (*lA)[72] = (ushort_t(*)[72])smem;
  ushort_t (*lB)[72] = (ushort_t(*)[72])(smem + 128*72);
  const int tid = threadIdx.x;
  const int lane = tid & 63, wid = tid >> 6;
  const int g = lane >> 4, lr = lane & 15;
  const int bx = blockIdx.x, bm = blockIdx.y * 128;
  const int bn = bx * 64;
  const int wm = (wid >> 1) * 64, wn = (wid & 1) * 32;
  f32x4 acc[4][2] = {};

  // prologue: stage K-tile 0
  {
    short8 nA[4], nB[2];
    #pragma unroll
    for (int it=0; it<4; ++it) { int fl = tid + it*256; nA[it] = *(const short8*)&A[(size_t)(bm + (fl>>3))*CC + (fl&7)*8]; }
    #pragma unroll
    for (int it=0; it<2; ++it) { int fl = tid + it*256; nB[it] = *(const short8*)&Bt[(size_t)(bn + (fl>>3))*CC + (fl&7)*8]; }
    #pragma unroll
    for (int it=0; it<4; ++it) { int fl = tid + it*256; *(short8*)&lA[fl>>3][(fl&7)*8] = nA[it]; }
    #pragma unroll
    for (int it=0; it<2; ++it) { int fl = tid + it*256; *(short8*)&lB[fl>>3][(fl&7)*8] = nB[it]; }
  }
  __syncthreads();

  #pragma unroll
  for (int t = 0; t < 8; ++t) {
    short8 nA[4], nB[2];
    if (t < 7) {
      int k0 = (t+1)*64;
      #pragma unroll
      for (int it=0; it<4; ++it) { int fl = tid + it*256; nA[it] = *(const short8*)&A[(size_t)(bm + (fl>>3))*CC + k0 + (fl&7)*8]; }
      #pragma unroll
      for (int it=0; it<2; ++it) { int fl = tid + it*256; nB[it] = *(const short8*)&Bt[(size_t)(bn + (fl>>3))*CC + k0 + (fl&7)*8]; }
    }
    short8 af[4][2], bf[2][2];
    #pragma unroll
    for (int mf=0; mf<4; ++mf)
      #pragma unroll
      for (int kk=0; kk<2; ++kk) af[mf][kk] = *(const short8*)&lA[wm + mf*16 + lr][kk*32 + g*8];
    #pragma unroll
    for (int nf=0; nf<2; ++nf)
      #pragma unroll
      for (int kk=0; kk<2; ++kk) bf[nf][kk] = *(const short8*)&lB[wn + nf*16 + lr][kk*32 + g*8];
    #pragma unroll
    for (int kk=0; kk<2; ++kk)
      #pragma unroll
      for (int mf=0; mf<4; ++mf)
        #pragma unroll
        for (int nf=0; nf<2; ++nf)
          acc[mf][nf] = MFMA16(af[mf][kk], bf[nf][kk], acc[mf][nf]);
    __syncthreads();
    if (t < 7) {
      #pragma unroll
      for (int it=0; it<4; ++it) { int fl = tid + it*256; *(short8*)&lA[fl>>3][(fl&7)*8] = nA[it]; }
      #pragma unroll
      for (int it=0; it<2; ++it) { int fl = tid + it*256; *(short8*)&lB[fl>>3][(fl&7)*8] = nB[it]; }
      __syncthreads();
    }
  }

  // epilogue
  const int third = bx >> 3, h = bx & 7;
  const int b0 = bm >> 11;
  const size_t bh = (size_t)(b0*HH + h);
  ushort_t (*ldsT)[136] = (ushort_t(*)[136])smem;   // reuse (all LDS reads done)
  #pragma unroll
  for (int mf=0; mf<4; ++mf) {
    #pragma unroll
    for (int nf=0; nf<2; ++nf) {
      int d = wn + nf*16 + lr;
      float bs = bias[third*512 + h*64 + d];
      #pragma unroll
      for (int r=0; r<4; ++r) {
        int tl = wm + mf*16 + g*4 + r;
        int mm = bm + tl;
        int tg = mm & 2047;
        float v = acc[mf][nf][r] + bs;
        if (third == 0) {
          phiQ[(bh*TT + tg)*DD + d] = f2bf(elu1(v));
        } else if (third == 1) {
          ushort_t e = f2bf(elu1(v) * mdiag[mm]);
          phiK[(bh*TT + tg)*DD + d] = e;
          ldsT[d][tl] = e;
        } else {
          ldsT[d][tl] = f2bf(v * mdiag[mm]);
        }
      }
    }
  }
  if (third >= 1) {
    __syncthreads();
    ushort_t* dst = (third == 1) ? kTc : vTc;
    int d = tid >> 2, q = tid & 3;
    int cl = q >> 1, tl0 = (q & 1) * 32;
    int c0 = ((bm & 2047) >> 6) + cl;
    size_t obase = ((bh*NCH + c0)*DD + d)*64 + tl0;
    #pragma unroll
    for (int j=0; j<4; ++j)
      *(short8*)&dst[obase + j*8] = *(const short8*)&ldsT[d][cl*64 + tl0 + j*8];
  }
}

// ---------- per-chunk state: 512 blocks x 4 waves (wave w = v-feature block nf=w; w0 also ones-row) ----------
// sChunk[cid][j][i] = sum_t V_aug[t][j] * phiK[t][i]
__global__ __launch_bounds__(256) void chunk_state(const ushort_t* __restrict__ kTc,
                                                   const ushort_t* __restrict__ vTc,
                                                   float* __restrict__ sChunk)
{
  int cid = blockIdx.x;                  // bh*NCH + c
  int w = threadIdx.x >> 6;
  int lane = threadIdx.x & 63, g = lane >> 4, lr = lane & 15;
  size_t base = (size_t)cid * (DD*64);
  short8 af[4][2];
  #pragma unroll
  for (int mf=0; mf<4; ++mf)
    #pragma unroll
    for (int kf=0; kf<2; ++kf)
      af[mf][kf] = *(const short8*)&kTc[base + (size_t)(mf*16+lr)*64 + kf*32 + g*8];
  float* dst = &sChunk[(size_t)cid * 5120];
  short8 bfr[2];
  #pragma unroll
  for (int kf=0; kf<2; ++kf)
    bfr[kf] = *(const short8*)&vTc[base + (size_t)(w*16+lr)*64 + kf*32 + g*8];
  #pragma unroll
  for (int mf=0; mf<4; ++mf) {
    f32x4 acc = {0.f,0.f,0.f,0.f};
    #pragma unroll
    for (int kf=0; kf<2; ++kf) acc = MFMA16(af[mf][kf], bfr[kf], acc);
    *(f32x4*)&dst[(size_t)(w*16+lr)*64 + mf*16 + g*4] = acc;
  }
  if (w == 0) {                          // ones-row block (j = 64..79; only j=64 nonzero)
    short8 onesf;
    short ov = (lr == 0) ? (short)0x3F80 : (short)0;
    #pragma unroll
    for (int j=0;j<8;++j) onesf[j] = ov;
    #pragma unroll
    for (int mf=0; mf<4; ++mf) {
      f32x4 acc = {0.f,0.f,0.f,0.f};
      #pragma unroll
      for (int kf=0; kf<2; ++kf) acc = MFMA16(af[mf][kf], onesf, acc);
      *(f32x4*)&dst[(size_t)(64+lr)*64 + mf*16 + g*4] = acc;
    }
  }
}

// ---------- exclusive prefix over chunks: 320 blocks x 64 thr, depth-2 prefetch ----------
__global__ __launch_bounds__(64) void scan_states(const float* __restrict__ sChunk, ushort_t* __restrict__ sPrev)
{
  int bx = blockIdx.x;                   // 16 bh x 20 segs
  int bh = bx / 20, seg = bx % 20;
  int e4 = seg*64 + threadIdx.x;         // 0..1279 f32x4 columns
  const f32x4* src = (const f32x4*)(sChunk + (size_t)bh*NCH*5120) + e4;
  us4* dst = (us4*)(sPrev + (size_t)bh*NCH*5120) + e4;
  f32x4 run = {0.f,0.f,0.f,0.f};
  f32x4 p0 = src[0];
  f32x4 p1 = src[1280];
  for (int c = 0; c < NCH; ++c) {
    f32x4 cur = p0; p0 = p1;
    if (c+2 < NCH) p1 = src[(size_t)(c+2)*1280];
    us4 o = { f2bf(run[0]), f2bf(run[1]), f2bf(run[2]), f2bf(run[3]) };
    dst[(size_t)c*1280] = o;
    run += cur;
  }
}

// ---------- per-chunk output: 512 single-wave blocks ----------
__global__ __launch_bounds__(64) void chunk_out(const ushort_t* __restrict__ phiQ,
    const ushort_t* __restrict__ phiK, const ushort_t* __restrict__ vTc,
    const ushort_t* __restrict__ sPrev, ushort_t* __restrict__ ya)
{
  __shared__ __align__(16) ushort_t P[64][72];
  int cid = blockIdx.x;
  int bh = cid >> 5, c = cid & 31;
  int lane = threadIdx.x, g = lane >> 4, lr = lane & 15;
  int t0 = c * 64;
  size_t qbase = (size_t)bh*TT + t0;
  size_t vbase = (size_t)cid * (DD*64);
  short8 qf[4][2];
  #pragma unroll
  for (int mf=0;mf<4;++mf)
    #pragma unroll
    for (int kf=0;kf<2;++kf)
      qf[mf][kf] = *(const short8*)&phiQ[(qbase + mf*16 + lr)*DD + kf*32 + g*8];
  // QK^T
  f32x4 accs[4][4] = {};
  #pragma unroll
  for (int nf=0;nf<4;++nf)
    #pragma unroll
    for (int kf=0;kf<2;++kf) {
      short8 bk = *(const short8*)&phiK[(qbase + nf*16 + lr)*DD + kf*32 + g*8];
      #pragma unroll
      for (int mf=0;mf<4;++mf) accs[mf][nf] = MFMA16(qf[mf][kf], bk, accs[mf][nf]);
    }
  // Q @ S_prev (cols 0..63 numerator, col 64 denominator prefix)
  f32x4 accn[4][5] = {};
  size_t sbase = (size_t)cid * 5120;
  #pragma unroll
  for (int nf=0;nf<5;++nf)
    #pragma unroll
    for (int kf=0;kf<2;++kf) {
      short8 bs = *(const short8*)&sPrev[sbase + (size_t)(nf*16+lr)*64 + kf*32 + g*8];
      #pragma unroll
      for (int mf=0;mf<4;++mf) accn[mf][nf] = MFMA16(qf[mf][kf], bs, accn[mf][nf]);
    }
  // masked P -> LDS (bf16)
  #pragma unroll
  for (int mf=0;mf<4;++mf)
    #pragma unroll
    for (int nf=0;nf<4;++nf)
      #pragma unroll
      for (int r=0;r<4;++r) {
        int t = mf*16 + g*4 + r, s = nf*16 + lr;
        P[t][s] = f2bf((s <= t) ? accs[mf][nf][r] : 0.f);
      }
  __syncthreads();
  short8 pf[4][2];
  #pragma unroll
  for (int mf=0;mf<4;++mf)
    #pragma unroll
    for (int kf=0;kf<2;++kf)
      pf[mf][kf] = *(const short8*)&P[mf*16+lr][kf*32 + g*8];
  // P @ V_aug
  short8 onesf;
  {
    short ov = (lr == 0) ? (short)0x3F80 : (short)0;
    #pragma unroll
    for (int j=0;j<8;++j) onesf[j] = ov;
  }
  #pragma unroll
  for (int nf=0;nf<5;++nf)
    #pragma unroll
    for (int kf=0;kf<2;++kf) {
      short8 vf = (nf < 4) ? *(const short8*)&vTc[vbase + (size_t)(nf*16+lr)*64 + kf*32 + g*8]
                           : onesf;
      #pragma unroll
      for (int mf=0;mf<4;++mf) accn[mf][nf] = MFMA16(pf[mf][kf], vf, accn[mf][nf]);
    }
  float invb[4][4];
  #pragma unroll
  for (int mf=0;mf<4;++mf)
    #pragma unroll
    for (int r=0;r<4;++r) {
      float iv = 1.0f / fmaxf(accn[mf][4][r], 1e-8f);
      invb[mf][r] = __shfl(iv, lane & 48);
    }
  int b = bh >> 3, h = bh & 7;
  #pragma unroll
  for (int mf=0;mf<4;++mf)
    #pragma unroll
    for (int nf=0;nf<4;++nf)
      #pragma unroll
      for (int r=0;r<4;++r) {
        int t = t0 + mf*16 + g*4 + r;
        int col = h*64 + nf*16 + lr;
        ya[((size_t)b*TT + t)*CC + col] = f2bf(accn[mf][nf][r] * invb[mf][r]);
      }
}

// ---------- GEMM3: 64x64 tile, BK=64, reg-staged pipeline; grid (8, 64) ----------
__global__ __launch_bounds__(256) void gemm_proj(const ushort_t* __restrict__ A, const ushort_t* __restrict__ Bt,
                                                 const float* __restrict__ bias, float* __restrict__ out)
{
  __shared__ __align__(16) ushort_t lA[64][72];
  __shared__ __align__(16) ushort_t lB[64][72];
  const int tid = threadIdx.x;
  const int lane = tid & 63, wid = tid >> 6;
  const int g = lane >> 4, lr = lane & 15;
  const int bm = blockIdx.y * 64, bn = blockIdx.x * 64;
  const int wm = (wid >> 1) * 32, wn = (wid & 1) * 32;
  f32x4 acc[2][2] = {};
  {
    short8 nA[2], nB[2];
    #pragma unroll
    for (int it=0; it<2; ++it) { int fl = tid + it*256; nA[it] = *(const short8*)&A[(size_t)(bm + (fl>>3))*CC + (fl&7)*8]; }
    #pragma unroll
    for (int it=0; it<2; ++it) { int fl = tid + it*256; nB[it] = *(const short8*)&Bt[(size_t)(bn + (fl>>3))*CC + (fl&7)*8]; }
    #pragma unroll
    for (int it=0; it<2; ++it) { int fl = tid + it*256; *(short8*)&lA[fl>>3][(fl&7)*8] = nA[it]; }
    #pragma unroll
    for (int it=0; it<2; ++it) { int fl = tid + it*256; *(short8*)&lB[fl>>3][(fl&7)*8] = nB[it]; }
  }
  __syncthreads();
  #pragma unroll
  for (int t = 0; t < 8; ++t) {
    short8 nA[2], nB[2];
    if (t < 7) {
      int k0 = (t+1)*64;
      #pragma unroll
      for (int it=0; it<2; ++it) { int fl = tid + it*256; nA[it] = *(const short8*)&A[(size_t)(bm + (fl>>3))*CC + k0 + (fl&7)*8]; }
      #pragma unroll
      for (int it=0; it<2; ++it) { int fl = tid + it*256; nB[it] = *(const short8*)&Bt[(size_t)(bn + (fl>>3))*CC + k0 + (fl&7)*8]; }
    }
    short8 af[2][2], bf[2][2];
    #pragma unroll
    for (int mf=0; mf<2; ++mf)
      #pragma unroll
      for (int kk=0; kk<2; ++kk) af[mf][kk] = *(const short8*)&lA[wm + mf*16 + lr][kk*32 + g*8];
    #pragma unroll
    for (int nf=0; nf<2; ++nf)
      #pragma unroll
      for (int kk=0; kk<2; ++kk) bf[nf][kk] = *(const short8*)&lB[wn + nf*16 + lr][kk*32 + g*8];
    #pragma unroll
    for (int kk=0; kk<2; ++kk)
      #pragma unroll
      for (int mf=0; mf<2; ++mf)
        #pragma unroll
        for (int nf=0; nf<2; ++nf)
          acc[mf][nf] = MFMA16(af[mf][kk], bf[nf][kk], acc[mf][nf]);
    __syncthreads();
    if (t < 7) {
      #pragma unroll
      for (int it=0; it<2; ++it) { int fl = tid + it*256; *(short8*)&lA[fl>>3][(fl&7)*8] = nA[it]; }
      #pragma unroll
      for (int it=0; it<2; ++it) { int fl = tid + it*256; *(short8*)&lB[fl>>3][(fl&7)*8] = nB[it]; }
      __syncthreads();
    }
  }
  #pragma unroll
  for (int mf=0; mf<2; ++mf) {
    int m0 = bm + wm + mf*16 + g*4;
    #pragma unroll
    for (int nf=0; nf<2; ++nf) {
      int n = bn + wn + nf*16 + lr;
      #pragma unroll
      for (int r=0; r<4; ++r)
        out[(size_t)(m0 + r)*CC + n] = acc[mf][nf][r] + bias[n];
    }
  }
}

extern "C" void kernel_launch(void* const* d_in, const int* in_sizes, int n_in,
                              void* d_out, int out_size, void* d_ws, size_t ws_size,
                              hipStream_t stream)
{
  const float* x     = (const float*)d_in[0];
  const float* amask = (const float*)d_in[1];
  const float* wqkv  = (const float*)d_in[2];
  const float* bqkv  = (const float*)d_in[3];
  const float* wproj = (const float*)d_in[4];
  const float* bproj = (const float*)d_in[5];
  float* out = (float*)d_out;
  char* ws = (char*)d_ws;

  ushort_t* xb    = (ushort_t*)(ws + 0);          // 4096x512 bf16      (4 MB)
  ushort_t* wt    = (ushort_t*)(ws + 4194304);    // 1536x512 bf16      (1.5 MB)
  ushort_t* pt    = (ushort_t*)(ws + 5767168);    // 512x512 bf16       (0.5 MB)
  float*    mdiag = (float*)   (ws + 6291456);    // 4096 f32
  ushort_t* phiQ  = (ushort_t*)(ws + 6307840);    // [bh][t][d] bf16    (4 MB)
  ushort_t* phiK  = (ushort_t*)(ws + 10502144);   // [bh][t][d] bf16    (4 MB)
  ushort_t* kTc   = (ushort_t*)(ws + 14696448);   // [bh][c][d][64]     (4 MB)
  ushort_t* vTc   = (ushort_t*)(ws + 18890752);   // [bh][c][d][64]     (4 MB)
  ushort_t* ya    = (ushort_t*)(ws + 23085056);   // 4096x512 bf16      (4 MB)
  float*    sChunk= (float*)   (ws + 27279360);   // 512 x 80x64 f32    (10.5 MB)
  ushort_t* sPrev = (ushort_t*)(ws + 37765120);   // 512 x 80x64 bf16   (5.25 MB)

  prep<<<dim3(1057), dim3(256), 0, stream>>>(x, amask, wqkv, wproj, xb, wt, pt, mdiag);
  gemm_qkv<<<dim3(24,32), dim3(256), 0, stream>>>(xb, wt, bqkv, mdiag, phiQ, phiK, kTc, vTc);
  chunk_state<<<dim3(512), dim3(256), 0, stream>>>(kTc, vTc, sChunk);
  scan_states<<<dim3(320), dim3(64), 0, stream>>>(sChunk, sPrev);
  chunk_out<<<dim3(512), dim3(64), 0, stream>>>(phiQ, phiK, vTc, sPrev, ya);
  gemm_proj<<<dim3(8,64), dim3(256), 0, stream>>>(ya, pt, bproj, out);
}